// Round 1
// baseline (891.380 us; speedup 1.0000x reference)
//
#include <hip/hip_runtime.h>
#include <hip/hip_bf16.h>

typedef __bf16 bf16x8 __attribute__((ext_vector_type(8)));
typedef float f32x4 __attribute__((ext_vector_type(4)));

#define DEVI __device__ __forceinline__

constexpr int N_TOK = 2048;   // B*T
constexpr int DIM   = 2048;   // D
constexpr int NEXP  = 64;     // E
constexpr int FDIM  = 512;    // F
constexpr int TOPK  = 4;      // K
constexpr int NSH   = 2;      // S
constexpr int HSH   = 2048;   // HS

constexpr int BM = 128, BN = 128, BK = 32, BKP = 40; // BKP pad: 80B rows, 16B-aligned

DEVI unsigned short f2b(float f) {
  union { float fv; unsigned u; } v; v.fv = f;
  unsigned r = v.u + 0x7fffu + ((v.u >> 16) & 1u);
  return (unsigned short)(r >> 16);
}
DEVI float b2f(unsigned short h) {
  union { unsigned u; float f; } v; v.u = ((unsigned)h) << 16;
  return v.f;
}

// ---------------- Router: logits, softmax, top-4, build expert lists ----------------
__global__ void router_kernel(const float* __restrict__ x, const float* __restrict__ rw,
                              const float* __restrict__ rb, int* __restrict__ cnt,
                              int* __restrict__ listTok, float* __restrict__ listW) {
  const int lane = threadIdx.x & 63;
  const int wave = threadIdx.x >> 6;
  const int tokBase = blockIdx.x * 8 + wave * 2;
  const float* __restrict__ xr0 = x + (size_t)tokBase * DIM;
  const float* __restrict__ xr1 = xr0 + DIM;
  float acc0 = 0.f, acc1 = 0.f;
  for (int d = 0; d < DIM; ++d) {
    const float r = rw[(size_t)d * NEXP + lane];
    acc0 = fmaf(xr0[d], r, acc0);
    acc1 = fmaf(xr1[d], r, acc1);
  }
  const float bias = rb[lane];
  #pragma unroll
  for (int t = 0; t < 2; ++t) {
    const float v = (t == 0) ? acc0 : acc1;
    const int token = tokBase + t;
    float m = v;
    #pragma unroll
    for (int o = 32; o > 0; o >>= 1) m = fmaxf(m, __shfl_xor(m, o));
    const float p = expf(v - m);
    float ss = p;
    #pragma unroll
    for (int o = 32; o > 0; o >>= 1) ss += __shfl_xor(ss, o);
    const float score = p / ss;
    float cur = v + bias;
    float wk[TOPK]; int ik[TOPK]; float wsum = 0.f;
    #pragma unroll
    for (int k = 0; k < TOPK; ++k) {
      float tm = cur;
      #pragma unroll
      for (int o = 32; o > 0; o >>= 1) tm = fmaxf(tm, __shfl_xor(tm, o));
      const unsigned long long msk = __ballot(cur == tm);
      const int sel = (int)__builtin_ctzll(msk);   // lowest index on ties (matches top_k)
      const float w = __shfl(score, sel);
      wk[k] = w; ik[k] = sel; wsum += w;
      if (lane == sel) cur = -3.4e38f;
    }
    if (lane < TOPK) {
      const int e = ik[lane];
      const float w = wk[lane] / wsum;
      const int slot = atomicAdd(&cnt[e], 1);
      listTok[(size_t)e * N_TOK + slot] = token;
      listW[(size_t)e * N_TOK + slot] = w;
    }
  }
}

__global__ void scan_kernel(const int* __restrict__ cnt, int* __restrict__ off) {
  if (threadIdx.x == 0) {
    int s = 0;
    for (int e = 0; e < NEXP; ++e) { off[e] = s; s += cnt[e]; }
  }
}

// ---------------- Up GEMM: H = X @ W  (GPASS: H = silu(X@Wg) * H * weight) ----------------
template<bool ROUTED, bool GPASS>
__global__ __launch_bounds__(256)
void up_gemm(const float* __restrict__ x, const float* __restrict__ W,
             const int* __restrict__ cnt, const int* __restrict__ off,
             const int* __restrict__ listTok, const float* __restrict__ listW,
             unsigned short* __restrict__ H, int Ftot) {
  const int tid = threadIdx.x;
  const int f0 = blockIdx.x * BN;
  const int e  = blockIdx.y;
  const int m0 = blockIdx.z * BM;
  int rcnt, rowbase;
  if (ROUTED) {
    const int c = cnt[e];
    if (m0 >= c) return;
    rcnt = min(BM, c - m0);
    rowbase = off[e] + m0;
  } else {
    rcnt = BM;
    rowbase = e * N_TOK + m0;
  }
  const float* __restrict__ wb = W + (size_t)e * DIM * Ftot;

  __shared__ __align__(16) unsigned short Al[BM][BKP];
  __shared__ __align__(16) unsigned short Bl[BN][BKP];
  __shared__ int   tokS[BM];
  __shared__ float wS[BM];

  if (tid < BM) {
    if (ROUTED) {
      const bool vld = tid < rcnt;
      tokS[tid] = listTok[(size_t)e * N_TOK + (vld ? m0 + tid : m0)];
      wS[tid]   = vld ? listW[(size_t)e * N_TOK + m0 + tid] : 0.f;
    } else {
      tokS[tid] = m0 + tid;
      wS[tid]   = 1.f;
    }
  }
  __syncthreads();

  int arow_[4], acol_[4];
  const float* asrc[4];
  #pragma unroll
  for (int j = 0; j < 4; ++j) {
    const int idx = j * 256 + tid;
    arow_[j] = idx >> 3;
    acol_[j] = (idx & 7) * 4;
    asrc[j] = x + (size_t)tokS[arow_[j]] * DIM + acol_[j];
  }

  const int wave = tid >> 6, l = tid & 63;
  const int wm = wave >> 1, wn = wave & 1;
  const int lc = l & 15;
  const int k8 = (l >> 4) * 8;

  f32x4 acc[4][4];
  #pragma unroll
  for (int i = 0; i < 4; ++i)
    #pragma unroll
    for (int j = 0; j < 4; ++j) acc[i][j] = f32x4{0.f, 0.f, 0.f, 0.f};

  for (int d0 = 0; d0 < DIM; d0 += BK) {
    #pragma unroll
    for (int j = 0; j < 4; ++j) {
      const float4 v = *reinterpret_cast<const float4*>(asrc[j] + d0);
      unsigned short* p = &Al[arow_[j]][acol_[j]];
      p[0] = f2b(v.x); p[1] = f2b(v.y); p[2] = f2b(v.z); p[3] = f2b(v.w);
    }
    #pragma unroll
    for (int j = 0; j < 16; ++j) {
      const int idx = j * 256 + tid;
      const int kk = idx >> 7;
      const int ff = idx & 127;
      Bl[ff][kk] = f2b(wb[(size_t)(d0 + kk) * Ftot + f0 + ff]);
    }
    __syncthreads();
    bf16x8 af[4], bq[4];
    #pragma unroll
    for (int i = 0; i < 4; ++i)
      af[i] = *reinterpret_cast<const bf16x8*>(&Al[wm * 64 + i * 16 + lc][k8]);
    #pragma unroll
    for (int i = 0; i < 4; ++i)
      bq[i] = *reinterpret_cast<const bf16x8*>(&Bl[wn * 64 + i * 16 + lc][k8]);
    #pragma unroll
    for (int mi = 0; mi < 4; ++mi)
      #pragma unroll
      for (int ni = 0; ni < 4; ++ni)
        acc[mi][ni] = __builtin_amdgcn_mfma_f32_16x16x32_bf16(af[mi], bq[ni], acc[mi][ni], 0, 0, 0);
    __syncthreads();
  }

  #pragma unroll
  for (int mi = 0; mi < 4; ++mi) {
    #pragma unroll
    for (int ni = 0; ni < 4; ++ni) {
      #pragma unroll
      for (int r = 0; r < 4; ++r) {
        const int row = wm * 64 + mi * 16 + (l >> 4) * 4 + r;
        if (row < rcnt) {
          const int col = f0 + wn * 64 + ni * 16 + lc;
          const size_t hidx = (size_t)(rowbase + row) * Ftot + col;
          const float v = acc[mi][ni][r];
          if (GPASS) {
            const float prev = b2f(H[hidx]);
            const float sg = v / (1.f + __expf(-v));
            H[hidx] = f2b(sg * prev * wS[row]);
          } else {
            H[hidx] = f2b(v);
          }
        }
      }
    }
  }
}

// ---------------- Down GEMM: out (+)= H @ Wd ----------------
template<bool ROUTED>
__global__ __launch_bounds__(256)
void down_gemm(const unsigned short* __restrict__ H, const float* __restrict__ Wd,
               const int* __restrict__ cnt, const int* __restrict__ off,
               const int* __restrict__ listTok, float* __restrict__ out, int Kd) {
  const int tid = threadIdx.x;
  const int x0 = blockIdx.x * BN;
  const int e  = blockIdx.y;
  const int m0 = blockIdx.z * BM;
  int rcnt, rowbase;
  if (ROUTED) {
    const int c = cnt[e];
    if (m0 >= c) return;
    rcnt = min(BM, c - m0);
    rowbase = off[e] + m0;
  } else {
    rcnt = BM;
    rowbase = m0;
  }
  __shared__ __align__(16) unsigned short Al[BM][BKP];
  __shared__ __align__(16) unsigned short Bl[BN][BKP];
  __shared__ int tokS[BM];
  if (ROUTED) {
    if (tid < BM) tokS[tid] = listTok[(size_t)e * N_TOK + m0 + min(tid, rcnt - 1)];
    __syncthreads();
  }

  int arow_[4], acol_[4];
  #pragma unroll
  for (int j = 0; j < 4; ++j) {
    const int idx = j * 256 + tid;
    arow_[j] = idx >> 3;
    acol_[j] = (idx & 7) * 4;
  }

  const int wave = tid >> 6, l = tid & 63;
  const int wm = wave >> 1, wn = wave & 1;
  const int lc = l & 15;
  const int k8 = (l >> 4) * 8;

  f32x4 acc[4][4];
  #pragma unroll
  for (int i = 0; i < 4; ++i)
    #pragma unroll
    for (int j = 0; j < 4; ++j) acc[i][j] = f32x4{0.f, 0.f, 0.f, 0.f};

  const int nS = ROUTED ? 1 : NSH;
  for (int s = 0; s < nS; ++s) {
    const unsigned short* __restrict__ Hb =
        ROUTED ? H + (size_t)rowbase * Kd : H + ((size_t)s * N_TOK + rowbase) * (size_t)Kd;
    const float* __restrict__ wb =
        ROUTED ? Wd + (size_t)e * FDIM * DIM : Wd + (size_t)s * HSH * DIM;
    for (int d0 = 0; d0 < Kd; d0 += BK) {
      #pragma unroll
      for (int j = 0; j < 4; ++j) {
        const int rr = min(arow_[j], rcnt - 1);
        const ushort4 v = *reinterpret_cast<const ushort4*>(Hb + (size_t)rr * Kd + d0 + acol_[j]);
        *reinterpret_cast<ushort4*>(&Al[arow_[j]][acol_[j]]) = v;
      }
      #pragma unroll
      for (int j = 0; j < 16; ++j) {
        const int idx = j * 256 + tid;
        const int kk = idx >> 7;
        const int ff = idx & 127;
        Bl[ff][kk] = f2b(wb[(size_t)(d0 + kk) * DIM + x0 + ff]);
      }
      __syncthreads();
      bf16x8 af[4], bq[4];
      #pragma unroll
      for (int i = 0; i < 4; ++i)
        af[i] = *reinterpret_cast<const bf16x8*>(&Al[wm * 64 + i * 16 + lc][k8]);
      #pragma unroll
      for (int i = 0; i < 4; ++i)
        bq[i] = *reinterpret_cast<const bf16x8*>(&Bl[wn * 64 + i * 16 + lc][k8]);
      #pragma unroll
      for (int mi = 0; mi < 4; ++mi)
        #pragma unroll
        for (int ni = 0; ni < 4; ++ni)
          acc[mi][ni] = __builtin_amdgcn_mfma_f32_16x16x32_bf16(af[mi], bq[ni], acc[mi][ni], 0, 0, 0);
      __syncthreads();
    }
  }

  #pragma unroll
  for (int mi = 0; mi < 4; ++mi) {
    #pragma unroll
    for (int ni = 0; ni < 4; ++ni) {
      #pragma unroll
      for (int r = 0; r < 4; ++r) {
        const int row = wm * 64 + mi * 16 + (l >> 4) * 4 + r;
        if (row < rcnt) {
          const int col = x0 + wn * 64 + ni * 16 + lc;
          if (ROUTED) {
            atomicAdd(&out[(size_t)tokS[row] * DIM + col], acc[mi][ni][r]);
          } else {
            out[(size_t)(rowbase + row) * DIM + col] = acc[mi][ni][r];
          }
        }
      }
    }
  }
}

extern "C" void kernel_launch(void* const* d_in, const int* in_sizes, int n_in,
                              void* d_out, int out_size, void* d_ws, size_t ws_size,
                              hipStream_t stream) {
  const float* x   = (const float*)d_in[0];
  const float* rw  = (const float*)d_in[1];
  const float* rb  = (const float*)d_in[2];
  const float* wg  = (const float*)d_in[3];
  const float* wu  = (const float*)d_in[4];
  const float* wd  = (const float*)d_in[5];
  const float* swg = (const float*)d_in[6];
  const float* swu = (const float*)d_in[7];
  const float* swd = (const float*)d_in[8];
  float* out = (float*)d_out;
  char* ws = (char*)d_ws;

  int* cnt = (int*)ws;                                   // 64 ints
  int* off = (int*)(ws + 256);                           // 64 ints
  int* listTok = (int*)(ws + 4096);                      // 64*2048 ints
  float* listW = (float*)(ws + 4096 + (size_t)NEXP * N_TOK * 4);
  unsigned short* Hr = (unsigned short*)(ws + 4096 + 2 * (size_t)NEXP * N_TOK * 4);   // 8192*512 bf16
  unsigned short* Hs = (unsigned short*)((char*)Hr + (size_t)N_TOK * TOPK * FDIM * 2); // 2*2048*2048 bf16

  hipMemsetAsync(cnt, 0, NEXP * sizeof(int), stream);
  router_kernel<<<N_TOK / 8, 256, 0, stream>>>(x, rw, rb, cnt, listTok, listW);
  scan_kernel<<<1, 64, 0, stream>>>(cnt, off);
  // routed experts: U pass then G pass (silu*u*weight fused)
  up_gemm<true,  false><<<dim3(FDIM / BN, NEXP, 16), 256, 0, stream>>>(x, wu, cnt, off, listTok, listW, Hr, FDIM);
  up_gemm<true,  true ><<<dim3(FDIM / BN, NEXP, 16), 256, 0, stream>>>(x, wg, cnt, off, listTok, listW, Hr, FDIM);
  // shared experts
  up_gemm<false, false><<<dim3(HSH / BN, NSH, N_TOK / BM), 256, 0, stream>>>(x, swu, cnt, off, listTok, listW, Hs, HSH);
  up_gemm<false, true ><<<dim3(HSH / BN, NSH, N_TOK / BM), 256, 0, stream>>>(x, swg, cnt, off, listTok, listW, Hs, HSH);
  // down: shared initializes out, routed atomically accumulates
  down_gemm<false><<<dim3(DIM / BN, 1, N_TOK / BM), 256, 0, stream>>>(Hs, swd, cnt, off, listTok, out, HSH);
  down_gemm<true ><<<dim3(DIM / BN, NEXP, 16), 256, 0, stream>>>(Hr, wd, cnt, off, listTok, out, FDIM);
}

// Round 2
// 693.367 us; speedup vs baseline: 1.2856x; 1.2856x over previous
//
#include <hip/hip_runtime.h>
#include <hip/hip_bf16.h>

typedef __bf16 bf16x8 __attribute__((ext_vector_type(8)));
typedef float f32x4 __attribute__((ext_vector_type(4)));
typedef unsigned short u16x4 __attribute__((ext_vector_type(4)));
typedef unsigned short u16x8 __attribute__((ext_vector_type(8)));

#define DEVI __device__ __forceinline__

constexpr int N_TOK = 2048;   // B*T
constexpr int DIM   = 2048;   // D
constexpr int NEXP  = 64;     // E
constexpr int FDIM  = 512;    // F
constexpr int TOPK  = 4;      // K
constexpr int NSH   = 2;      // S
constexpr int HSH   = 2048;   // HS

constexpr int BM = 128, BN = 128, BK = 64, KS = 8;  // KS = BK/8 ksub planes

DEVI unsigned short f2b(float f) {
  union { float fv; unsigned u; } v; v.fv = f;
  unsigned r = v.u + 0x7fffu + ((v.u >> 16) & 1u);
  return (unsigned short)(r >> 16);
}
DEVI float b2f(unsigned short h) {
  union { unsigned u; float f; } v; v.u = ((unsigned)h) << 16;
  return v.f;
}
DEVI void gll16(const void* g, void* l) {
  __builtin_amdgcn_global_load_lds((const __attribute__((address_space(1))) unsigned*)g,
                                   (__attribute__((address_space(3))) unsigned*)l, 16, 0, 0);
}

// ---------------- x -> bf16 ----------------
__global__ void cvt_x_kernel(const float* __restrict__ x, unsigned short* __restrict__ xb) {
  const size_t i = ((size_t)blockIdx.x * 256 + threadIdx.x) * 8;
  const float4 a = *reinterpret_cast<const float4*>(x + i);
  const float4 b = *reinterpret_cast<const float4*>(x + i + 4);
  u16x8 o;
  o[0] = f2b(a.x); o[1] = f2b(a.y); o[2] = f2b(a.z); o[3] = f2b(a.w);
  o[4] = f2b(b.x); o[5] = f2b(b.y); o[6] = f2b(b.z); o[7] = f2b(b.w);
  *reinterpret_cast<u16x8*>(xb + i) = o;
}

// ---------------- shared weights: transpose + bf16 (2048x2048 slices) ----------------
__global__ __launch_bounds__(256)
void tr_shared_kernel(const float* __restrict__ swu, const float* __restrict__ swg,
                      const float* __restrict__ swd, unsigned short* __restrict__ swuT,
                      unsigned short* __restrict__ swgT, unsigned short* __restrict__ swdT) {
  __shared__ float Lf[64][68];
  const int tid = threadIdx.x;
  const int r0 = blockIdx.x * 64, c0 = blockIdx.y * 64;
  const int z = blockIdx.z, mat = z >> 1;
  const size_t soff = (size_t)(z & 1) * DIM * HSH;
  const float* in = (mat == 0 ? swu : mat == 1 ? swg : swd) + soff;
  unsigned short* ot = (mat == 0 ? swuT : mat == 1 ? swgT : swdT) + soff;
  #pragma unroll
  for (int j = 0; j < 4; ++j) {
    const int idx = j * 1024 + tid * 4;
    const int row = idx >> 6, col = idx & 63;
    const float4 v = *reinterpret_cast<const float4*>(in + (size_t)(r0 + row) * 2048 + c0 + col);
    *reinterpret_cast<float4*>(&Lf[row][col]) = v;
  }
  __syncthreads();
  #pragma unroll
  for (int j = 0; j < 4; ++j) {
    const int idx = j * 1024 + tid * 4;
    const int orow = idx >> 6, ocol = idx & 63;
    u16x4 o;
    o[0] = f2b(Lf[ocol][orow]);     o[1] = f2b(Lf[ocol + 1][orow]);
    o[2] = f2b(Lf[ocol + 2][orow]); o[3] = f2b(Lf[ocol + 3][orow]);
    *reinterpret_cast<u16x4*>(ot + (size_t)(c0 + orow) * 2048 + r0 + ocol) = o;
  }
}

// ---------------- Router ----------------
__global__ void router_kernel(const float* __restrict__ x, const float* __restrict__ rw,
                              const float* __restrict__ rb, int* __restrict__ cnt,
                              int* __restrict__ listTok, float* __restrict__ listW) {
  const int lane = threadIdx.x & 63;
  const int wave = threadIdx.x >> 6;
  const int tokBase = blockIdx.x * 8 + wave * 2;
  const float* __restrict__ xr0 = x + (size_t)tokBase * DIM;
  const float* __restrict__ xr1 = xr0 + DIM;
  float acc0 = 0.f, acc1 = 0.f;
  for (int d = 0; d < DIM; ++d) {
    const float r = rw[(size_t)d * NEXP + lane];
    acc0 = fmaf(xr0[d], r, acc0);
    acc1 = fmaf(xr1[d], r, acc1);
  }
  const float bias = rb[lane];
  #pragma unroll
  for (int t = 0; t < 2; ++t) {
    const float v = (t == 0) ? acc0 : acc1;
    const int token = tokBase + t;
    float m = v;
    #pragma unroll
    for (int o = 32; o > 0; o >>= 1) m = fmaxf(m, __shfl_xor(m, o));
    const float p = expf(v - m);
    float ss = p;
    #pragma unroll
    for (int o = 32; o > 0; o >>= 1) ss += __shfl_xor(ss, o);
    const float score = p / ss;
    float cur = v + bias;
    float wk[TOPK]; int ik[TOPK]; float wsum = 0.f;
    #pragma unroll
    for (int k = 0; k < TOPK; ++k) {
      float tm = cur;
      #pragma unroll
      for (int o = 32; o > 0; o >>= 1) tm = fmaxf(tm, __shfl_xor(tm, o));
      const unsigned long long msk = __ballot(cur == tm);
      const int sel = (int)__builtin_ctzll(msk);
      const float w = __shfl(score, sel);
      wk[k] = w; ik[k] = sel; wsum += w;
      if (lane == sel) cur = -3.4e38f;
    }
    if (lane < TOPK) {
      const int e = ik[lane];
      const float w = wk[lane] / wsum;
      const int slot = atomicAdd(&cnt[e], 1);
      listTok[(size_t)e * N_TOK + slot] = token;
      listW[(size_t)e * N_TOK + slot] = w;
    }
  }
}

__global__ void scan_kernel(const int* __restrict__ cnt, int* __restrict__ off) {
  if (threadIdx.x == 0) {
    int s = 0;
    for (int e = 0; e < NEXP; ++e) { off[e] = s; s += cnt[e]; }
  }
}

// ---------------- Fused up: U = X@Wu, G = X@Wg, H = silu(G)*U*w ----------------
template<bool ROUTED>
__global__ __launch_bounds__(256, 2)
void up_fused_kernel(const unsigned short* __restrict__ xb,
                     const float* __restrict__ Wu, const float* __restrict__ Wg,
                     const unsigned short* __restrict__ WuT, const unsigned short* __restrict__ WgT,
                     const int* __restrict__ cnt, const int* __restrict__ off,
                     const int* __restrict__ listTok, const float* __restrict__ listW,
                     unsigned short* __restrict__ H) {
  const int Ftot = ROUTED ? FDIM : HSH;
  const int tid = threadIdx.x;
  const int f0 = blockIdx.x * BN;
  const int e  = blockIdx.y;
  const int m0 = blockIdx.z * BM;
  int rcnt, rowbase;
  if (ROUTED) {
    const int c = cnt[e];
    if (m0 >= c) return;
    rcnt = min(BM, c - m0);
    rowbase = off[e] + m0;
  } else {
    rcnt = BM;
    rowbase = e * N_TOK + m0;
  }

  __shared__ __align__(16) unsigned short Al[KS][BM][8];
  __shared__ __align__(16) unsigned short Bu[KS][BN][8];
  __shared__ __align__(16) unsigned short Bg[KS][BN][8];
  __shared__ int tokS[BM];
  __shared__ float wS[BM];

  if (tid < BM) {
    if (ROUTED) {
      const bool v = tid < rcnt;
      tokS[tid] = listTok[(size_t)e * N_TOK + m0 + (v ? tid : 0)];
      wS[tid]   = v ? listW[(size_t)e * N_TOK + m0 + tid] : 0.f;
    } else { tokS[tid] = m0 + tid; wS[tid] = 1.f; }
  }
  __syncthreads();

  const int wid = tid >> 6, l = tid & 63;
  const int wm = wid >> 1, wn = wid & 1;
  const int lc = l & 15, hi = l >> 4;

  // per-lane A row pointers (gathered tokens)
  const unsigned short* pa0 = xb + (size_t)tokS[l] * DIM;
  const unsigned short* pa1 = xb + (size_t)tokS[64 + l] * DIM;

  // shared: per-lane transposed-weight row pointers
  const unsigned short *pbu0 = nullptr, *pbu1 = nullptr, *pbg0 = nullptr, *pbg1 = nullptr;
  if constexpr (!ROUTED) {
    const unsigned short* wut = WuT + (size_t)e * HSH * DIM;
    const unsigned short* wgt = WgT + (size_t)e * HSH * DIM;
    pbu0 = wut + (size_t)(f0 + l) * DIM;  pbu1 = wut + (size_t)(f0 + 64 + l) * DIM;
    pbg0 = wgt + (size_t)(f0 + l) * DIM;  pbg1 = wgt + (size_t)(f0 + 64 + l) * DIM;
  }
  // routed: f32 column-staging setup
  const int bf = tid & 127, kh = tid >> 7;
  const float *wpu = nullptr, *wpg = nullptr;
  if constexpr (ROUTED) {
    wpu = Wu + (size_t)e * DIM * FDIM + (size_t)(kh * 32) * FDIM + f0 + bf;
    wpg = Wg + (size_t)e * DIM * FDIM + (size_t)(kh * 32) * FDIM + f0 + bf;
  }
  unsigned short* bdstU = &Bu[kh * 4][bf][0];
  unsigned short* bdstG = &Bg[kh * 4][bf][0];

  f32x4 au[4][4], ag[4][4];
  #pragma unroll
  for (int i = 0; i < 4; ++i)
    #pragma unroll
    for (int j = 0; j < 4; ++j) { au[i][j] = f32x4{0,0,0,0}; ag[i][j] = f32x4{0,0,0,0}; }

  for (int d0 = 0; d0 < DIM; d0 += BK) {
    // A: async global->LDS, planes 2w,2w+1, halves 0/1
    gll16(pa0 + d0 + (2 * wid) * 8,     &Al[2 * wid][0][0]);
    gll16(pa1 + d0 + (2 * wid) * 8,     &Al[2 * wid][64][0]);
    gll16(pa0 + d0 + (2 * wid + 1) * 8, &Al[2 * wid + 1][0][0]);
    gll16(pa1 + d0 + (2 * wid + 1) * 8, &Al[2 * wid + 1][64][0]);
    if constexpr (!ROUTED) {
      gll16(pbu0 + d0 + (2 * wid) * 8,     &Bu[2 * wid][0][0]);
      gll16(pbu1 + d0 + (2 * wid) * 8,     &Bu[2 * wid][64][0]);
      gll16(pbu0 + d0 + (2 * wid + 1) * 8, &Bu[2 * wid + 1][0][0]);
      gll16(pbu1 + d0 + (2 * wid + 1) * 8, &Bu[2 * wid + 1][64][0]);
      gll16(pbg0 + d0 + (2 * wid) * 8,     &Bg[2 * wid][0][0]);
      gll16(pbg1 + d0 + (2 * wid) * 8,     &Bg[2 * wid][64][0]);
      gll16(pbg0 + d0 + (2 * wid + 1) * 8, &Bg[2 * wid + 1][0][0]);
      gll16(pbg1 + d0 + (2 * wid + 1) * 8, &Bg[2 * wid + 1][64][0]);
    } else {
      float r[32];
      #pragma unroll
      for (int j = 0; j < 32; ++j) r[j] = wpu[(size_t)(d0 + j) * FDIM];
      #pragma unroll
      for (int jg = 0; jg < 4; ++jg) {
        u16x8 pk;
        #pragma unroll
        for (int q = 0; q < 8; ++q) pk[q] = f2b(r[jg * 8 + q]);
        *reinterpret_cast<u16x8*>(bdstU + jg * BN * 8) = pk;
      }
      #pragma unroll
      for (int j = 0; j < 32; ++j) r[j] = wpg[(size_t)(d0 + j) * FDIM];
      #pragma unroll
      for (int jg = 0; jg < 4; ++jg) {
        u16x8 pk;
        #pragma unroll
        for (int q = 0; q < 8; ++q) pk[q] = f2b(r[jg * 8 + q]);
        *reinterpret_cast<u16x8*>(bdstG + jg * BN * 8) = pk;
      }
    }
    __syncthreads();
    #pragma unroll
    for (int ks = 0; ks < 2; ++ks) {
      bf16x8 af[4], bu_[4], bg_[4];
      #pragma unroll
      for (int i = 0; i < 4; ++i)
        af[i] = *reinterpret_cast<const bf16x8*>(&Al[ks * 4 + hi][wm * 64 + i * 16 + lc][0]);
      #pragma unroll
      for (int i = 0; i < 4; ++i) {
        bu_[i] = *reinterpret_cast<const bf16x8*>(&Bu[ks * 4 + hi][wn * 64 + i * 16 + lc][0]);
        bg_[i] = *reinterpret_cast<const bf16x8*>(&Bg[ks * 4 + hi][wn * 64 + i * 16 + lc][0]);
      }
      #pragma unroll
      for (int mi = 0; mi < 4; ++mi)
        #pragma unroll
        for (int ni = 0; ni < 4; ++ni) {
          au[mi][ni] = __builtin_amdgcn_mfma_f32_16x16x32_bf16(af[mi], bu_[ni], au[mi][ni], 0, 0, 0);
          ag[mi][ni] = __builtin_amdgcn_mfma_f32_16x16x32_bf16(af[mi], bg_[ni], ag[mi][ni], 0, 0, 0);
        }
    }
    __syncthreads();
  }

  #pragma unroll
  for (int mi = 0; mi < 4; ++mi)
    #pragma unroll
    for (int ni = 0; ni < 4; ++ni)
      #pragma unroll
      for (int r2 = 0; r2 < 4; ++r2) {
        const int row = wm * 64 + mi * 16 + hi * 4 + r2;
        if (row < rcnt) {
          const int col = f0 + wn * 64 + ni * 16 + lc;
          const float g = ag[mi][ni][r2], u = au[mi][ni][r2];
          const float h = (g / (1.f + __expf(-g))) * u * wS[row];
          H[(size_t)(rowbase + row) * Ftot + col] = f2b(h);
        }
      }
}

// ---------------- Merged down: out += H @ Wd (atomic; routed y<64, shared y=64,65) ----------------
__global__ __launch_bounds__(256, 2)
void down_kernel(const unsigned short* __restrict__ Hr, const unsigned short* __restrict__ Hs,
                 const float* __restrict__ wd, const unsigned short* __restrict__ swdT,
                 const int* __restrict__ cnt, const int* __restrict__ off,
                 const int* __restrict__ listTok, float* __restrict__ out) {
  const int tid = threadIdx.x;
  const int x0 = blockIdx.x * BN;
  const int y  = blockIdx.y;
  const int m0 = blockIdx.z * BM;
  const bool routed = y < NEXP;
  int rcnt, Kd;
  const unsigned short* Ab;
  const float* wb = nullptr;
  const unsigned short* wbT = nullptr;

  __shared__ int tokS[BM];
  __shared__ __align__(16) unsigned short Al[KS][BM][8];
  __shared__ __align__(16) unsigned short Bl[KS][BN][8];

  if (routed) {
    const int c = cnt[y];
    if (m0 >= c) return;
    rcnt = min(BM, c - m0); Kd = FDIM;
    Ab = Hr + (size_t)(off[y] + m0) * FDIM;
    wb = wd + (size_t)y * FDIM * DIM;
    if (tid < BM) tokS[tid] = listTok[(size_t)y * N_TOK + m0 + min(tid, rcnt - 1)];
  } else {
    const int s = y - NEXP;
    rcnt = BM; Kd = HSH;
    Ab = Hs + ((size_t)s * N_TOK + m0) * HSH;
    wbT = swdT + (size_t)s * HSH * DIM;   // [D][HS] bf16
    if (tid < BM) tokS[tid] = m0 + tid;
  }
  __syncthreads();

  const int wid = tid >> 6, l = tid & 63;
  const int wm = wid >> 1, wn = wid & 1;
  const int lc = l & 15, hi = l >> 4;

  const unsigned short* pA = Ab + (size_t)l * Kd;
  const unsigned short *pBT0 = nullptr, *pBT1 = nullptr;
  if (!routed) {
    pBT0 = wbT + (size_t)(x0 + l) * HSH;
    pBT1 = wbT + (size_t)(x0 + 64 + l) * HSH;
  }
  const int bf = tid & 127, kh = tid >> 7;
  const float* wp = routed ? wb + (size_t)(kh * 32) * DIM + x0 + bf : nullptr;
  unsigned short* bdst = &Bl[kh * 4][bf][0];

  f32x4 acc[4][4];
  #pragma unroll
  for (int i = 0; i < 4; ++i)
    #pragma unroll
    for (int j = 0; j < 4; ++j) acc[i][j] = f32x4{0,0,0,0};

  for (int d0 = 0; d0 < Kd; d0 += BK) {
    gll16(pA + d0 + (2 * wid) * 8,                       &Al[2 * wid][0][0]);
    gll16(pA + (size_t)64 * Kd + d0 + (2 * wid) * 8,     &Al[2 * wid][64][0]);
    gll16(pA + d0 + (2 * wid + 1) * 8,                   &Al[2 * wid + 1][0][0]);
    gll16(pA + (size_t)64 * Kd + d0 + (2 * wid + 1) * 8, &Al[2 * wid + 1][64][0]);
    if (routed) {
      float r[32];
      #pragma unroll
      for (int j = 0; j < 32; ++j) r[j] = wp[(size_t)(d0 + j) * DIM];
      #pragma unroll
      for (int jg = 0; jg < 4; ++jg) {
        u16x8 pk;
        #pragma unroll
        for (int q = 0; q < 8; ++q) pk[q] = f2b(r[jg * 8 + q]);
        *reinterpret_cast<u16x8*>(bdst + jg * BN * 8) = pk;
      }
    } else {
      gll16(pBT0 + d0 + (2 * wid) * 8,     &Bl[2 * wid][0][0]);
      gll16(pBT1 + d0 + (2 * wid) * 8,     &Bl[2 * wid][64][0]);
      gll16(pBT0 + d0 + (2 * wid + 1) * 8, &Bl[2 * wid + 1][0][0]);
      gll16(pBT1 + d0 + (2 * wid + 1) * 8, &Bl[2 * wid + 1][64][0]);
    }
    __syncthreads();
    #pragma unroll
    for (int ks = 0; ks < 2; ++ks) {
      bf16x8 af[4], bq[4];
      #pragma unroll
      for (int i = 0; i < 4; ++i)
        af[i] = *reinterpret_cast<const bf16x8*>(&Al[ks * 4 + hi][wm * 64 + i * 16 + lc][0]);
      #pragma unroll
      for (int i = 0; i < 4; ++i)
        bq[i] = *reinterpret_cast<const bf16x8*>(&Bl[ks * 4 + hi][wn * 64 + i * 16 + lc][0]);
      #pragma unroll
      for (int mi = 0; mi < 4; ++mi)
        #pragma unroll
        for (int ni = 0; ni < 4; ++ni)
          acc[mi][ni] = __builtin_amdgcn_mfma_f32_16x16x32_bf16(af[mi], bq[ni], acc[mi][ni], 0, 0, 0);
    }
    __syncthreads();
  }

  #pragma unroll
  for (int mi = 0; mi < 4; ++mi)
    #pragma unroll
    for (int ni = 0; ni < 4; ++ni)
      #pragma unroll
      for (int r2 = 0; r2 < 4; ++r2) {
        const int row = wm * 64 + mi * 16 + hi * 4 + r2;
        if (row < rcnt) {
          const int col = x0 + wn * 64 + ni * 16 + lc;
          atomicAdd(&out[(size_t)tokS[row] * DIM + col], acc[mi][ni][r2]);
        }
      }
}

extern "C" void kernel_launch(void* const* d_in, const int* in_sizes, int n_in,
                              void* d_out, int out_size, void* d_ws, size_t ws_size,
                              hipStream_t stream) {
  const float* x   = (const float*)d_in[0];
  const float* rw  = (const float*)d_in[1];
  const float* rb  = (const float*)d_in[2];
  const float* wg  = (const float*)d_in[3];
  const float* wu  = (const float*)d_in[4];
  const float* wd  = (const float*)d_in[5];
  const float* swg = (const float*)d_in[6];
  const float* swu = (const float*)d_in[7];
  const float* swd = (const float*)d_in[8];
  float* out = (float*)d_out;
  char* ws = (char*)d_ws;

  int* cnt = (int*)ws;
  int* off = (int*)(ws + 256);
  int* listTok = (int*)(ws + 4096);
  float* listW = (float*)(ws + 4096 + 512 * 1024);
  unsigned short* xb   = (unsigned short*)(ws + (size_t) 2 * 1024 * 1024);  // 8 MB
  unsigned short* Hr   = (unsigned short*)(ws + (size_t)10 * 1024 * 1024);  // 8 MB
  unsigned short* Hs   = (unsigned short*)(ws + (size_t)18 * 1024 * 1024);  // 16 MB
  unsigned short* swuT = (unsigned short*)(ws + (size_t)34 * 1024 * 1024);  // 16 MB
  unsigned short* swgT = (unsigned short*)(ws + (size_t)50 * 1024 * 1024);  // 16 MB
  unsigned short* swdT = (unsigned short*)(ws + (size_t)66 * 1024 * 1024);  // 16 MB -> 82 MB

  hipMemsetAsync(cnt, 0, NEXP * sizeof(int), stream);
  hipMemsetAsync(out, 0, (size_t)N_TOK * DIM * sizeof(float), stream);
  cvt_x_kernel<<<(N_TOK * DIM) / (256 * 8), 256, 0, stream>>>(x, xb);
  tr_shared_kernel<<<dim3(32, 32, 6), 256, 0, stream>>>(swu, swg, swd, swuT, swgT, swdT);
  router_kernel<<<N_TOK / 8, 256, 0, stream>>>(x, rw, rb, cnt, listTok, listW);
  scan_kernel<<<1, 64, 0, stream>>>(cnt, off);
  up_fused_kernel<true ><<<dim3(FDIM / BN, NEXP, 16), 256, 0, stream>>>(
      xb, wu, wg, nullptr, nullptr, cnt, off, listTok, listW, Hr);
  up_fused_kernel<false><<<dim3(HSH / BN, NSH, N_TOK / BM), 256, 0, stream>>>(
      xb, nullptr, nullptr, swuT, swgT, cnt, off, listTok, listW, Hs);
  down_kernel<<<dim3(DIM / BN, NEXP + NSH, 16), 256, 0, stream>>>(
      Hr, Hs, wd, swdT, cnt, off, listTok, out);
}